// Round 12
// baseline (355.479 us; speedup 1.0000x reference)
//
#include <hip/hip_runtime.h>
#include <hip/hip_bf16.h>
#include <math.h>

// Shapes are fixed by the problem instance.
#define BDOCS   1024
#define CNODES  4096
#define INDIM   768
#define HID     512
#define NHEAD   4
#define HDIM    128
#define NEG_SLOPE 0.2f

#define KSPLIT  8
#define JPER    (CNODES / KSPLIT)   // 512
#define NCH     (JPER / 32)         // 16

typedef __attribute__((ext_vector_type(8))) short short8;   // 8 bf16 (4 VGPRs)
typedef __attribute__((ext_vector_type(4))) float f32x4;    // MFMA C/D

__device__ __forceinline__ float lrelu(float x) { return x > 0.f ? x : NEG_SLOPE * x; }

// float -> bf16 bits, round-to-nearest-even
__device__ __forceinline__ short f2bf(float f) {
    union { float f; unsigned u; } v; v.f = f;
    unsigned r = (v.u + 0x7fff + ((v.u >> 16) & 1)) >> 16;
    return (short)r;
}
__device__ __forceinline__ float bf2f(short s) {
    union { float f; unsigned u; } v; v.u = ((unsigned)(unsigned short)s) << 16;
    return v.f;
}
__device__ __forceinline__ unsigned pk2(float a, float b) {
    union { float f; unsigned u; } x, y; x.f = a; y.f = b;
    unsigned lo = (x.u + 0x7fff + ((x.u >> 16) & 1)) >> 16;
    unsigned hi = (y.u + 0x7fff + ((y.u >> 16) & 1)) >> 16;
    return lo | (hi << 16);
}
// half-up round f32 -> bf16 (hot loop; w in [0,1])
__device__ __forceinline__ short hup(float f) {
    union { float f; unsigned u; } v; v.f = f;
    return (short)((v.u + 0x8000) >> 16);
}
// monotone float<->uint encoding for atomicMax on floats
__device__ __forceinline__ unsigned encf(float x) {
    union { float f; unsigned u; } v; v.f = x;
    return (v.u & 0x80000000u) ? ~v.u : (v.u | 0x80000000u);
}
__device__ __forceinline__ float decf(unsigned u) {
    union { float f; unsigned u; } v;
    v.u = (u & 0x80000000u) ? (u ^ 0x80000000u) : ~u;
    return v.f;
}

// ---------------------------------------------------------------------------
// prep helpers as device functions (shared LDS tile passed in)
// ---------------------------------------------------------------------------
__device__ void frag_T_dev(const float* __restrict__ src, short* __restrict__ dst,
                           int N, int K, int jc, int nq, float (*tile)[132])
{
    const int t  = threadIdx.x;
    const int KC = K >> 5;
#pragma unroll
    for (int it = 0; it < 16; it++) {
        const int e = it * 256 + t;
        const int j = e >> 7, n = e & 127;
        tile[j][n] = src[(size_t)(jc * 32 + j) * N + nq * 128 + n];
    }
    __syncthreads();
#pragma unroll
    for (int s = 0; s < 2; s++) {
        const int item = s * 256 + t;
        const int nbl = item >> 6, lane = item & 63;
        const int nr = lane & 15, kq = lane >> 4;
        short8 v;
#pragma unroll
        for (int jr = 0; jr < 8; jr++)
            v[jr] = f2bf(tile[kq * 8 + jr][nbl * 16 + nr]);
        *(short8*)&dst[((size_t)((nq * 8 + nbl) * KC + jc) * 64 + lane) * 8] = v;
    }
}

__device__ void frag_A_dev(const float* __restrict__ src, short* __restrict__ dst,
                           int C, int rb, int cq, float (*tile)[132])
{
    const int t  = threadIdx.x;
    const int KC = C >> 5;
#pragma unroll
    for (int it = 0; it < 8; it++) {
        const int e = it * 256 + t;
        const int r = e >> 7, c = e & 127;
        tile[r][c] = src[(size_t)(rb * 16 + r) * C + cq * 128 + c];
    }
    __syncthreads();
    const int kcl = t >> 6, lane = t & 63;
    const int m = lane & 15, kq = lane >> 4;
    short8 v8;
#pragma unroll
    for (int j = 0; j < 8; j++) v8[j] = f2bf(tile[m][kcl * 32 + kq * 8 + j]);
    *(short8*)&dst[((size_t)(rb * KC + cq * 4 + kcl) * 64 + lane) * 8] = v8;
}

// ---------------------------------------------------------------------------
// prep_all: pack_adj (65536 blocks) + zero asrc/adst (32 blocks) +
// frag_T(Wd/W1/W2) + frag_A(doc_x, label_init), flattened into one grid.
// Inits the 16 MhEnc slots to enc(-inf). Replaces the first hipMemsetAsync.
// ---------------------------------------------------------------------------
#define PREP_BLOCKS (65536 + 32 + 96 + 96 + 64 + 384 + 1536)
__global__ __launch_bounds__(256)
void prep_all(const int* __restrict__ adj, unsigned long long* __restrict__ adjb64,
              const float* __restrict__ Wd, short* __restrict__ Wdf,
              const float* __restrict__ W1, short* __restrict__ W1f,
              const float* __restrict__ W2, short* __restrict__ W2f,
              const float* __restrict__ doc_x, short* __restrict__ dxf,
              const float* __restrict__ label_init, short* __restrict__ lif,
              unsigned* __restrict__ MhEnc, float4* __restrict__ accZero)
{
    __shared__ float tile[32][132];
    int b = blockIdx.x;
    if (b < 65536) {
        if (b == 0 && threadIdx.x < 16) MhEnc[threadIdx.x] = 0x007FFFFFu;  // enc(-inf)
        const int t    = threadIdx.x;
        const int gw   = b * 4 + (t >> 6);
        const int lane = t & 63;
        const int i  = gw >> 6;
        const int j0 = (gw & 63) * 64;
        const int a  = adj[(size_t)i * CNODES + j0 + lane];
        const unsigned long long msk = __ballot(a != 0);
        if (lane == 0) adjb64[(size_t)i * 64 + (j0 >> 6)] = msk;
        return;
    }
    b -= 65536;
    if (b < 32) {  // zero asrc+adst (contiguous, 2*NHEAD*CNODES floats = 8192 float4)
        accZero[b * 256 + threadIdx.x] = (float4){0.f, 0.f, 0.f, 0.f};
        return;
    }
    b -= 32;
    if (b < 96)  { frag_T_dev(Wd, Wdf, HID, INDIM, b % 24, b / 24, tile); return; }
    b -= 96;
    if (b < 96)  { frag_T_dev(W1, W1f, HID, INDIM, b % 24, b / 24, tile); return; }
    b -= 96;
    if (b < 64)  { frag_T_dev(W2, W2f, HID, HID, b % 16, b / 16, tile); return; }
    b -= 64;
    if (b < 384) { frag_A_dev(doc_x, dxf, INDIM, b % 64, b / 64, tile); return; }
    b -= 384;
    frag_A_dev(label_init, lif, INDIM, b % 256, b / 256, tile);
}

// ---------------------------------------------------------------------------
// hpre body: hpre tile = A @ B^T, n-split by half-head. (mb, h*2+ch) covers
// rows [mb*16,+16) x cols [h*128+ch*64,+64) (4 B-frags, 5 loads/kc).
// K-loop unroll 4 (deeper load pipeline for the L2-latency-bound regime).
// Epilogue: (a) half-B-frags of bf16(hpre) -> hbTf, (b) asrc/adst half-dots
// -> deterministic 2-way atomicAdd, (c) wave max -> atomicMax MhEncH.
// ---------------------------------------------------------------------------
template <int KC>
__device__ void hpre_body(const short* __restrict__ Af, const short* __restrict__ Bf,
                          const float* __restrict__ a_src, const float* __restrict__ a_dst,
                          short* __restrict__ hbTf, float* __restrict__ asrc,
                          float* __restrict__ adst, unsigned* __restrict__ MhEncH,
                          int mb, int hy)
{
    __shared__ __align__(16) short tileT[64][24];   // [localcol][localrow]
    const int lane = threadIdx.x;
    const int h    = hy >> 1;   // head
    const int ch   = hy & 1;    // col half
    const int i0   = mb * 16;

    f32x4 acc[4];
#pragma unroll
    for (int c = 0; c < 4; c++) acc[c] = (f32x4){0.f, 0.f, 0.f, 0.f};

    const short* ap = Af + (size_t)mb * KC * 512 + lane * 8;
    const short* bp = Bf + (size_t)(h * 8 + ch * 4) * KC * 512 + lane * 8;

#pragma unroll 4
    for (int kc = 0; kc < KC; kc++) {
        short8 a = *(const short8*)(ap + (size_t)kc * 512);
#pragma unroll
        for (int c = 0; c < 4; c++) {
            short8 bf = *(const short8*)(bp + ((size_t)c * KC + kc) * 512);
            acc[c] = __builtin_amdgcn_mfma_f32_16x16x32_bf16(a, bf, acc[c], 0, 0, 0);
        }
    }

    const int col = lane & 15, q4 = lane >> 4;

#pragma unroll
    for (int c = 0; c < 4; c++) {
        uint2 u;
        u.x = pk2(acc[c][0], acc[c][1]);
        u.y = pk2(acc[c][2], acc[c][3]);
        *(uint2*)&tileT[c * 16 + col][q4 * 4] = u;
    }
    __syncthreads();
    {
        const int jc = mb >> 1, khalf = mb & 1;
        const int nr = lane & 15, kq = lane >> 4;
        if ((kq >> 1) == khalf) {
#pragma unroll
            for (int cl = 0; cl < 4; cl++) {
                short8 v = *(const short8*)&tileT[cl * 16 + nr][(kq & 1) * 8];
                const int nbl = h * 8 + ch * 4 + cl;
                *(short8*)&hbTf[(((size_t)nbl * (CNODES / 32) + jc) * 64 + lane) * 8] = v;
            }
        }
    }

    float ssrc[4] = {}, sdst[4] = {};
#pragma unroll
    for (int c = 0; c < 4; c++) {
        const float vs = a_src[h * 128 + ch * 64 + c * 16 + col];
        const float vd = a_dst[h * 128 + ch * 64 + c * 16 + col];
#pragma unroll
        for (int r = 0; r < 4; r++) {
            ssrc[r] += acc[c][r] * vs;
            sdst[r] += acc[c][r] * vd;
        }
    }
#pragma unroll
    for (int mask = 1; mask <= 8; mask <<= 1)
#pragma unroll
        for (int r = 0; r < 4; r++) {
            ssrc[r] += __shfl_xor(ssrc[r], mask);
            sdst[r] += __shfl_xor(sdst[r], mask);
        }
    if (col == 0) {
#pragma unroll
        for (int r = 0; r < 4; r++) {
            const int row = i0 + q4 * 4 + r;
            atomicAdd(asrc + h * CNODES + row, ssrc[r]);   // exactly 2 contributors
            atomicAdd(adst + h * CNODES + row, sdst[r]);
        }
    }
    // wave max of half-dot -> one atomic per block
    float wmax = fmaxf(fmaxf(sdst[0], sdst[1]), fmaxf(sdst[2], sdst[3]));
    wmax = fmaxf(wmax, __shfl_xor(wmax, 16));
    wmax = fmaxf(wmax, __shfl_xor(wmax, 32));
    if (lane == 0) atomicMax(MhEncH + h * 2 + ch, encf(wmax));
}

// ---------------------------------------------------------------------------
// doc body: doc_h tile = relu(A @ B^T + bias) -> bf16 A-frags (dhf).
// K-loop unroll 4.
// ---------------------------------------------------------------------------
template <int KC>
__device__ void doc_body(const short* __restrict__ Af, const short* __restrict__ Bf,
                         const float* __restrict__ bias, short* __restrict__ dhf,
                         int mb, int ng)
{
    __shared__ __align__(16) short tile[16][32];
    const int lane = threadIdx.x;

    f32x4 acc[2];
#pragma unroll
    for (int c = 0; c < 2; c++) acc[c] = (f32x4){0.f, 0.f, 0.f, 0.f};

    const short* ap = Af + (size_t)mb * KC * 512 + lane * 8;
    const short* bp = Bf + (size_t)(ng * 2) * KC * 512 + lane * 8;

#pragma unroll 4
    for (int kc = 0; kc < KC; kc++) {
        short8 a = *(const short8*)(ap + (size_t)kc * 512);
#pragma unroll
        for (int c = 0; c < 2; c++) {
            short8 bf = *(const short8*)(bp + ((size_t)c * KC + kc) * 512);
            acc[c] = __builtin_amdgcn_mfma_f32_16x16x32_bf16(a, bf, acc[c], 0, 0, 0);
        }
    }

    const int col = lane & 15, q4 = lane >> 4;
#pragma unroll
    for (int c = 0; c < 2; c++)
#pragma unroll
        for (int r = 0; r < 4; r++) {
            float v = fmaxf(acc[c][r] + bias[ng * 32 + c * 16 + col], 0.f);
            tile[q4 * 4 + r][c * 16 + col] = f2bf(v);
        }
    __syncthreads();
    const int m = lane & 15, kq = lane >> 4;
    short8 v = *(const short8*)&tile[m][kq * 8];
    *(short8*)&dhf[(((size_t)mb * 16 + ng) * 64 + lane) * 8] = v;
}

// ---------------------------------------------------------------------------
// gemm_hd: fused hpre-L1 (2048 blocks) + doc (1024 blocks). The two are
// independent (both depend only on prep_all) -- fusing lets doc's blocks
// execute concurrently with hpre's instead of serializing on the stream.
// ---------------------------------------------------------------------------
template <int KC>
__global__ __launch_bounds__(64)
void gemm_hd(const short* __restrict__ Af, const short* __restrict__ Bf,
             const float* __restrict__ a_src, const float* __restrict__ a_dst,
             short* __restrict__ hbTf, float* __restrict__ asrc,
             float* __restrict__ adst, unsigned* __restrict__ MhEncH,
             const short* __restrict__ dAf, const short* __restrict__ dBf,
             const float* __restrict__ bias, short* __restrict__ dhf)
{
    const int b = blockIdx.x;
    if (b < 2048) {
        hpre_body<KC>(Af, Bf, a_src, a_dst, hbTf, asrc, adst, MhEncH, b >> 3, b & 7);
    } else {
        const int d = b - 2048;
        doc_body<KC>(dAf, dBf, bias, dhf, d >> 4, d & 15);
    }
}

// ---------------------------------------------------------------------------
// gemm_hpre: standalone (layer 2). grid (CNODES/16, 8).
// ---------------------------------------------------------------------------
template <int KC>
__global__ __launch_bounds__(64)
void gemm_hpre(const short* __restrict__ Af, const short* __restrict__ Bf,
               const float* __restrict__ a_src, const float* __restrict__ a_dst,
               short* __restrict__ hbTf, float* __restrict__ asrc, float* __restrict__ adst,
               unsigned* __restrict__ MhEncH)
{
    hpre_body<KC>(Af, Bf, a_src, a_dst, hbTf, asrc, adst, MhEncH,
                  blockIdx.x, blockIdx.y);
}

// ---------------------------------------------------------------------------
// gemm_frag: C[M][N] fp32 = A @ B^T from bf16 fragments (logits).
// m-tile 64, n-tile 64: per k-step 8 loads : 16 MFMA; K-loop unroll 4
// (deeper load pipeline -- 1 wave/SIMD resident, ILP must hide L2 latency).
// grid (BDOCS/64, CNODES/64) = (16, 64) = 1024 one-wave blocks.
// ---------------------------------------------------------------------------
template <int KC>
__global__ __launch_bounds__(64)
void gemm_frag(const short* __restrict__ Af, const short* __restrict__ Bf,
               float* __restrict__ Cmat, int N)
{
    const int lane = threadIdx.x;
    const int mb0  = blockIdx.x * 4;
    const int ng   = blockIdx.y;    // 64-col group

    f32x4 acc[4][4];
#pragma unroll
    for (int f = 0; f < 4; f++)
#pragma unroll
        for (int c = 0; c < 4; c++) acc[f][c] = (f32x4){0.f, 0.f, 0.f, 0.f};

    const short* ap = Af + (size_t)mb0 * KC * 512 + lane * 8;
    const short* bp = Bf + (size_t)(ng * 4) * KC * 512 + lane * 8;

#pragma unroll 4
    for (int kc = 0; kc < KC; kc++) {
        short8 a0 = *(const short8*)(ap + ((size_t)0 * KC + kc) * 512);
        short8 a1 = *(const short8*)(ap + ((size_t)1 * KC + kc) * 512);
        short8 a2 = *(const short8*)(ap + ((size_t)2 * KC + kc) * 512);
        short8 a3 = *(const short8*)(ap + ((size_t)3 * KC + kc) * 512);
#pragma unroll
        for (int c = 0; c < 4; c++) {
            short8 bf = *(const short8*)(bp + ((size_t)c * KC + kc) * 512);
            acc[0][c] = __builtin_amdgcn_mfma_f32_16x16x32_bf16(a0, bf, acc[0][c], 0, 0, 0);
            acc[1][c] = __builtin_amdgcn_mfma_f32_16x16x32_bf16(a1, bf, acc[1][c], 0, 0, 0);
            acc[2][c] = __builtin_amdgcn_mfma_f32_16x16x32_bf16(a2, bf, acc[2][c], 0, 0, 0);
            acc[3][c] = __builtin_amdgcn_mfma_f32_16x16x32_bf16(a3, bf, acc[3][c], 0, 0, 0);
        }
    }

    const int col = lane & 15, q4 = lane >> 4;
#pragma unroll
    for (int f = 0; f < 4; f++)
#pragma unroll
        for (int c = 0; c < 4; c++)
#pragma unroll
            for (int r = 0; r < 4; r++) {
                const int row = (mb0 + f) * 16 + q4 * 4 + r;
                Cmat[(size_t)row * N + ng * 64 + c * 16 + col] = acc[f][c][r];
            }
}

// ---------------------------------------------------------------------------
// attn_pv: partial[ks][i][n] (bf16) = sum_{j in slice} w_ij * V[j][n].
// 512-thread blocks = 8 waves (wave = (i-half, head)), E1/E2 in LDS preamble,
// Mh = sum of half maxima (upper bound; weights exact). grid (64, 8).
// BYTE-IDENTICAL to the 57.9us round-1 version: the 88-VGPR deep-prefetch
// schedule is fragile -- max-form weights, union packs, and s_setprio all
// collapsed it to a 76-VGPR shallow schedule (80-95us). DO NOT TOUCH.
// ---------------------------------------------------------------------------
__global__ __launch_bounds__(512, 2)
void attn_pv(const short* __restrict__ hbTf,
             const unsigned int* __restrict__ adjb,
             const float* __restrict__ asrc, const float* __restrict__ adst,
             const unsigned* __restrict__ MhEncH,
             short* __restrict__ part, float* __restrict__ lpart)
{
    __shared__ __align__(16) float E1s[NHEAD][512];    // 8 KB
    __shared__ __align__(16) float E2s[NHEAD][512];    // 8 KB
    __shared__ __align__(16) short tileO[32][520];     // 33.3 KB

    const int t    = threadIdx.x;
    const int ww   = t >> 6;
    const int w    = ww & 3;        // head
    const int f2   = ww >> 2;       // i-half (0/1)
    const int lane = t & 63;
    const int m    = lane & 15;
    const int kq   = lane >> 4;
    const int i0   = blockIdx.x * 64;
    const int iw   = i0 + f2 * 32;
    const int ks   = blockIdx.y;
    const int js   = ks * JPER;

    // ---- preamble: E1/E2 for this slice into LDS (t indexes j) ----
    {
        const int j = js + t;
#pragma unroll
        for (int h = 0; h < NHEAD; h++) {
            const float mhh = decf(MhEncH[h * 2]) + decf(MhEncH[h * 2 + 1]);
            const float d = adst[h * CNODES + j] - mhh;
            E1s[h][t] = __expf(d);
            E2s[h][t] = __expf(0.2f * d);
        }
    }

    const float mh  = decf(MhEncH[w * 2]) + decf(MhEncH[w * 2 + 1]);
    const float as0 = asrc[w * CNODES + iw + m];
    const float as1 = asrc[w * CNODES + iw + 16 + m];
    const float mr0 = lrelu(as0 + mh), mr1 = lrelu(as1 + mh);
    const float A10 = __expf(as0 + mh - mr0),          A11 = __expf(as1 + mh - mr1);
    const float A20 = __expf(0.2f * (as0 + mh) - mr0), A21 = __expf(0.2f * (as1 + mh) - mr1);
    const float T00 = __expf(-as0 - mh),               T01 = __expf(-as1 - mh);

    f32x4 acc[2][8], accO[2];
#pragma unroll
    for (int f = 0; f < 2; f++) {
        accO[f] = (f32x4){0.f, 0.f, 0.f, 0.f};
#pragma unroll
        for (int c = 0; c < 8; c++) acc[f][c] = (f32x4){0.f, 0.f, 0.f, 0.f};
    }
    short8 ones;
#pragma unroll
    for (int q = 0; q < 8; q++) ones[q] = (short)0x3F80;   // bf16 1.0

    const unsigned int* ar0 = adjb + (size_t)(iw + m) * 128 + ks * NCH;
    const unsigned int* ar1 = adjb + (size_t)(iw + 16 + m) * 128 + ks * NCH;

    __syncthreads();   // E LDS ready

#pragma unroll 2
    for (int ch = 0; ch < NCH; ch++) {
        const int jl = ch * 32;
        const unsigned int aw0 = ar0[ch] >> (kq * 8);
        const unsigned int aw1 = ar1[ch] >> (kq * 8);
        const float4 x0 = *(const float4*)&E1s[w][jl + kq * 8];
        const float4 x1 = *(const float4*)&E1s[w][jl + kq * 8 + 4];
        const float4 y0 = *(const float4*)&E2s[w][jl + kq * 8];
        const float4 y1 = *(const float4*)&E2s[w][jl + kq * 8 + 4];
        const float e1v[8] = {x0.x, x0.y, x0.z, x0.w, x1.x, x1.y, x1.z, x1.w};
        const float e2v[8] = {y0.x, y0.y, y0.z, y0.w, y1.x, y1.y, y1.z, y1.w};

        short8 a0, a1;
#pragma unroll
        for (int q = 0; q < 8; q++) {
            const float e1 = e1v[q], e2 = e2v[q];
            const bool c0 = e1 > T00, c1 = e1 > T01;
            float w0 = (c0 ? A10 : A20) * (c0 ? e1 : e2);
            float w1 = (c1 ? A11 : A21) * (c1 ? e1 : e2);
            w0 = ((aw0 >> q) & 1u) ? w0 : 0.f;
            w1 = ((aw1 >> q) & 1u) ? w1 : 0.f;
            a0[q] = hup(w0);
            a1[q] = hup(w1);
        }

        const short* bbase = hbTf + (((size_t)(w * 8) * 128 + ((js + jl) >> 5)) * 64 + lane) * 8;
#pragma unroll
        for (int c = 0; c < 8; c++) {
            short8 bf = *(const short8*)(bbase + (size_t)c * 128 * 64 * 8);
            acc[0][c] = __builtin_amdgcn_mfma_f32_16x16x32_bf16(a0, bf, acc[0][c], 0, 0, 0);
            acc[1][c] = __builtin_amdgcn_mfma_f32_16x16x32_bf16(a1, bf, acc[1][c], 0, 0, 0);
        }
        accO[0] = __builtin_amdgcn_mfma_f32_16x16x32_bf16(a0, ones, accO[0], 0, 0, 0);
        accO[1] = __builtin_amdgcn_mfma_f32_16x16x32_bf16(a1, ones, accO[1], 0, 0, 0);
    }

    if (m == 0) {
#pragma unroll
        for (int f = 0; f < 2; f++)
#pragma unroll
            for (int r = 0; r < 4; r++)
                lpart[((size_t)ks * NHEAD + w) * CNODES + iw + f * 16 + kq * 4 + r] = accO[f][r];
    }

    // bf16 partials via 32-row LDS tile, one round per i-half
    short* pS = part + (size_t)ks * CNODES * HID;
    for (int half = 0; half < 2; half++) {
        __syncthreads();
        if (f2 == half) {
#pragma unroll
            for (int f = 0; f < 2; f++)
#pragma unroll
                for (int c = 0; c < 8; c++)
#pragma unroll
                    for (int r = 0; r < 4; r++)
                        tileO[f * 16 + kq * 4 + r][w * 128 + c * 16 + m] = f2bf(acc[f][c][r]);
        }
        __syncthreads();
#pragma unroll
        for (int it = 0; it < 4; it++) {
            const int u   = it * 512 + t;
            const int row = u >> 6, un = u & 63;
            uint4 v = *(const uint4*)&tileO[row][un * 8];
            *(uint4*)&pS[(size_t)(i0 + half * 32 + row) * HID + un * 8] = v;
        }
    }
}

// ---------------------------------------------------------------------------
// reduce_norm_frag: out = (sum_s part)/(sum_s lpart), optional ELU, written
// as bf16 fragments. Coalesced: one wave reads one (s,i) row contiguously
// (64 lanes x 16B = 1KB); accumulate in registers, normalize, stage 16-row
// tile in LDS, emit fragments. Grid: CNODES/16 = 256 blocks x 256 threads.
// When ZERO (layer-1 pass), the first 32 blocks also zero asrc/adst for L2.
// ---------------------------------------------------------------------------
template <bool ELU, bool ZERO>
__global__ __launch_bounds__(256)
void reduce_norm_frag(const short* __restrict__ part, const float* __restrict__ lpart,
                      short* __restrict__ dst, float4* __restrict__ accZero)
{
    __shared__ __align__(16) short rowbuf[16][520];   // 16.6 KB, stride 1040B (2-way max)

    const int t    = threadIdx.x;
    const int wv   = t >> 6;        // wave 0..3
    const int lane = t & 63;
    const int rb   = blockIdx.x;    // 16-row block

    if (ZERO && blockIdx.x < 32)
        accZero[blockIdx.x * 256 + t] = (float4){0.f, 0.f, 0.f, 0.f};

    const int h = lane >> 4;        // head for this lane's column range (n0 = lane*8)

#pragma unroll
    for (int r = 0; r < 4; r++) {
        const int i = rb * 16 + wv * 4 + r;
        float v[8] = {};
        float l = 0.f;
#pragma unroll
        for (int s = 0; s < KSPLIT; s++) {
            const uint4 raw = *(const uint4*)&part[(size_t)s * CNODES * HID
                                                   + (size_t)i * HID + lane * 8];
            const unsigned rr[4] = {raw.x, raw.y, raw.z, raw.w};
#pragma unroll
            for (int q = 0; q < 4; q++) {
                v[q * 2]     += bf2f((short)(rr[q] & 0xffff));
                v[q * 2 + 1] += bf2f((short)(rr[q] >> 16));
            }
            l += lpart[((size_t)s * NHEAD + h) * CNODES + i];
        }
        const float inv = 1.0f / l;
        short8 o;
#pragma unroll
        for (int q = 0; q < 8; q++) {
            float x = v[q] * inv;
            if (ELU) x = x > 0.f ? x : (__expf(x) - 1.f);
            o[q] = f2bf(x);
        }
        *(short8*)&rowbuf[wv * 4 + r][lane * 8] = o;
    }
    __syncthreads();

    const int m  = lane & 15;
    const int kq = lane >> 4;
#pragma unroll
    for (int j = 0; j < 4; j++) {
        const int kc = wv + j * 4;
        short8 v = *(const short8*)&rowbuf[m][kc * 32 + kq * 8];
        *(short8*)&dst[(((size_t)rb * 16 + kc) * 64 + lane) * 8] = v;
    }
}

// ---------------------------------------------------------------------------
extern "C" void kernel_launch(void* const* d_in, const int* in_sizes, int n_in,
                              void* d_out, int out_size, void* d_ws, size_t ws_size,
                              hipStream_t stream)
{
    const float* doc_x      = (const float*)d_in[0];
    const float* label_init = (const float*)d_in[1];
    const int*   adj        = (const int*)d_in[2];
    const float* W1         = (const float*)d_in[3];
    const float* a_src1     = (const float*)d_in[4];
    const float* a_dst1     = (const float*)d_in[5];
    const float* W2         = (const float*)d_in[6];
    const float* a_src2     = (const float*)d_in[7];
    const float* a_dst2     = (const float*)d_in[8];
    const float* Wd         = (const float*)d_in[9];
    const float* bd         = (const float*)d_in[10];
    float*       out        = (float*)d_out;

    char* wsb = (char*)d_ws;
    size_t off = 0;
    auto alloc = [&](size_t bytes) -> char* {
        char* p = wsb + off;
        off = (off + bytes + 255) & ~(size_t)255;
        return p;
    };

    float* asrc  = (float*)alloc(NHEAD * CNODES * 4);   // zeroed in-kernel
    float* adst  = (float*)alloc(NHEAD * CNODES * 4);   // contiguous after asrc
    unsigned* MhEncH = (unsigned*)alloc(256);           // 0..7 L1 halves, 8..15 L2
    float* lpart = (float*)alloc((size_t)KSPLIT * NHEAD * CNODES * 4);
    unsigned int* adjb = (unsigned int*)alloc((size_t)CNODES * 128 * 4);   // 2 MB
    short* hbTf  = (short*)alloc((size_t)CNODES * HID * 2);                // 4 MB
    short* Wdf   = (short*)alloc((size_t)INDIM * HID * 2);
    short* W1f   = (short*)alloc((size_t)INDIM * HID * 2);
    short* W2f   = (short*)alloc((size_t)HID * HID * 2);
    short* dxf   = (short*)alloc((size_t)BDOCS * INDIM * 2);
    short* Af_li = (short*)alloc((size_t)CNODES * INDIM * 2);              // 6 MB
    short* Af2   = (short*)alloc((size_t)CNODES * HID * 2);                // 4 MB
    short* lhf   = (short*)alloc((size_t)CNODES * HID * 2);                // 4 MB
    short* dhf   = (short*)alloc((size_t)BDOCS * HID * 2);                 // 1 MB
    short* part  = (short*)alloc((size_t)KSPLIT * CNODES * HID * 2);       // 32 MB
    (void)ws_size;

    const dim3 blk(256);

    // all one-time transforms + asrc/adst zeroing in a single dispatch
    prep_all<<<PREP_BLOCKS, blk, 0, stream>>>(adj, (unsigned long long*)adjb,
                                              Wd, Wdf, W1, W1f, W2, W2f,
                                              doc_x, dxf, label_init, Af_li, MhEncH,
                                              (float4*)asrc);

    // fused: hpre1 (label_init @ W1 -> hbTf/asrc/adst/Mh) + doc_h (relu gemm)
    gemm_hd<INDIM / 32><<<2048 + 1024, 64, 0, stream>>>(
        Af_li, W1f, a_src1, a_dst1, hbTf, asrc, adst, MhEncH,
        dxf, Wdf, bd, dhf);

    // GAT layer 1
    attn_pv<<<dim3(CNODES / 64, KSPLIT), 512, 0, stream>>>(
        hbTf, adjb, asrc, adst, MhEncH, part, lpart);
    reduce_norm_frag<true, true><<<CNODES / 16, blk, 0, stream>>>(
        part, lpart, Af2, (float4*)asrc);   // also zeroes asrc/adst for L2

    // hpre2 = elu(gat1) @ W2 -> hbTf B-frags + asrc/adst + Mh halves (fused)
    gemm_hpre<HID / 32><<<dim3(CNODES / 16, 2 * NHEAD), 64, 0, stream>>>(
        Af2, W2f, a_src2, a_dst2, hbTf, asrc, adst, MhEncH + 8);

    // GAT layer 2
    attn_pv<<<dim3(CNODES / 64, KSPLIT), 512, 0, stream>>>(
        hbTf, adjb, asrc, adst, MhEncH + 8, part, lpart);
    reduce_norm_frag<false, false><<<CNODES / 16, blk, 0, stream>>>(
        part, lpart, lhf, nullptr);

    // logits = doc_h @ label_h^T -> out (64x64 tiles, 1024 blocks)
    gemm_frag<HID / 32><<<dim3(BDOCS / 64, CNODES / 64), 64, 0, stream>>>(dhf, lhf, out, CNODES);
}

// Round 13
// 350.894 us; speedup vs baseline: 1.0131x; 1.0131x over previous
//
#include <hip/hip_runtime.h>
#include <hip/hip_bf16.h>
#include <math.h>

// Shapes are fixed by the problem instance.
#define BDOCS   1024
#define CNODES  4096
#define INDIM   768
#define HID     512
#define NHEAD   4
#define HDIM    128
#define NEG_SLOPE 0.2f

#define KSPLIT  8
#define JPER    (CNODES / KSPLIT)   // 512
#define NCH     (JPER / 32)         // 16

typedef __attribute__((ext_vector_type(8))) short short8;   // 8 bf16 (4 VGPRs)
typedef __attribute__((ext_vector_type(4))) float f32x4;    // MFMA C/D

__device__ __forceinline__ float lrelu(float x) { return x > 0.f ? x : NEG_SLOPE * x; }

// float -> bf16 bits, round-to-nearest-even
__device__ __forceinline__ short f2bf(float f) {
    union { float f; unsigned u; } v; v.f = f;
    unsigned r = (v.u + 0x7fff + ((v.u >> 16) & 1)) >> 16;
    return (short)r;
}
__device__ __forceinline__ float bf2f(short s) {
    union { float f; unsigned u; } v; v.u = ((unsigned)(unsigned short)s) << 16;
    return v.f;
}
__device__ __forceinline__ unsigned pk2(float a, float b) {
    union { float f; unsigned u; } x, y; x.f = a; y.f = b;
    unsigned lo = (x.u + 0x7fff + ((x.u >> 16) & 1)) >> 16;
    unsigned hi = (y.u + 0x7fff + ((y.u >> 16) & 1)) >> 16;
    return lo | (hi << 16);
}
// half-up round f32 -> bf16 (hot loop; w in [0,1])
__device__ __forceinline__ short hup(float f) {
    union { float f; unsigned u; } v; v.f = f;
    return (short)((v.u + 0x8000) >> 16);
}
// monotone float<->uint encoding for atomicMax on floats
__device__ __forceinline__ unsigned encf(float x) {
    union { float f; unsigned u; } v; v.f = x;
    return (v.u & 0x80000000u) ? ~v.u : (v.u | 0x80000000u);
}
__device__ __forceinline__ float decf(unsigned u) {
    union { float f; unsigned u; } v;
    v.u = (u & 0x80000000u) ? (u ^ 0x80000000u) : ~u;
    return v.f;
}

// ---------------------------------------------------------------------------
// prep helpers as device functions (shared LDS tile passed in)
// ---------------------------------------------------------------------------
__device__ void frag_T_dev(const float* __restrict__ src, short* __restrict__ dst,
                           int N, int K, int jc, int nq, float (*tile)[132])
{
    const int t  = threadIdx.x;
    const int KC = K >> 5;
#pragma unroll
    for (int it = 0; it < 16; it++) {
        const int e = it * 256 + t;
        const int j = e >> 7, n = e & 127;
        tile[j][n] = src[(size_t)(jc * 32 + j) * N + nq * 128 + n];
    }
    __syncthreads();
#pragma unroll
    for (int s = 0; s < 2; s++) {
        const int item = s * 256 + t;
        const int nbl = item >> 6, lane = item & 63;
        const int nr = lane & 15, kq = lane >> 4;
        short8 v;
#pragma unroll
        for (int jr = 0; jr < 8; jr++)
            v[jr] = f2bf(tile[kq * 8 + jr][nbl * 16 + nr]);
        *(short8*)&dst[((size_t)((nq * 8 + nbl) * KC + jc) * 64 + lane) * 8] = v;
    }
}

__device__ void frag_A_dev(const float* __restrict__ src, short* __restrict__ dst,
                           int C, int rb, int cq, float (*tile)[132])
{
    const int t  = threadIdx.x;
    const int KC = C >> 5;
#pragma unroll
    for (int it = 0; it < 8; it++) {
        const int e = it * 256 + t;
        const int r = e >> 7, c = e & 127;
        tile[r][c] = src[(size_t)(rb * 16 + r) * C + cq * 128 + c];
    }
    __syncthreads();
    const int kcl = t >> 6, lane = t & 63;
    const int m = lane & 15, kq = lane >> 4;
    short8 v8;
#pragma unroll
    for (int j = 0; j < 8; j++) v8[j] = f2bf(tile[m][kcl * 32 + kq * 8 + j]);
    *(short8*)&dst[((size_t)(rb * KC + cq * 4 + kcl) * 64 + lane) * 8] = v8;
}

// ---------------------------------------------------------------------------
// prep_all: pack_adj (65536 blocks) + zero asrc/adst (32 blocks) +
// frag_T(Wd/W1/W2) + frag_A(doc_x, label_init), flattened into one grid.
// Inits the 16 MhEnc slots to enc(-inf). Replaces the first hipMemsetAsync.
// ---------------------------------------------------------------------------
#define PREP_BLOCKS (65536 + 32 + 96 + 96 + 64 + 384 + 1536)
__global__ __launch_bounds__(256)
void prep_all(const int* __restrict__ adj, unsigned long long* __restrict__ adjb64,
              const float* __restrict__ Wd, short* __restrict__ Wdf,
              const float* __restrict__ W1, short* __restrict__ W1f,
              const float* __restrict__ W2, short* __restrict__ W2f,
              const float* __restrict__ doc_x, short* __restrict__ dxf,
              const float* __restrict__ label_init, short* __restrict__ lif,
              unsigned* __restrict__ MhEnc, float4* __restrict__ accZero)
{
    __shared__ float tile[32][132];
    int b = blockIdx.x;
    if (b < 65536) {
        if (b == 0 && threadIdx.x < 16) MhEnc[threadIdx.x] = 0x007FFFFFu;  // enc(-inf)
        const int t    = threadIdx.x;
        const int gw   = b * 4 + (t >> 6);
        const int lane = t & 63;
        const int i  = gw >> 6;
        const int j0 = (gw & 63) * 64;
        const int a  = adj[(size_t)i * CNODES + j0 + lane];
        const unsigned long long msk = __ballot(a != 0);
        if (lane == 0) adjb64[(size_t)i * 64 + (j0 >> 6)] = msk;
        return;
    }
    b -= 65536;
    if (b < 32) {  // zero asrc+adst (contiguous, 2*NHEAD*CNODES floats = 8192 float4)
        accZero[b * 256 + threadIdx.x] = (float4){0.f, 0.f, 0.f, 0.f};
        return;
    }
    b -= 32;
    if (b < 96)  { frag_T_dev(Wd, Wdf, HID, INDIM, b % 24, b / 24, tile); return; }
    b -= 96;
    if (b < 96)  { frag_T_dev(W1, W1f, HID, INDIM, b % 24, b / 24, tile); return; }
    b -= 96;
    if (b < 64)  { frag_T_dev(W2, W2f, HID, HID, b % 16, b / 16, tile); return; }
    b -= 64;
    if (b < 384) { frag_A_dev(doc_x, dxf, INDIM, b % 64, b / 64, tile); return; }
    b -= 384;
    frag_A_dev(label_init, lif, INDIM, b % 256, b / 256, tile);
}

// ---------------------------------------------------------------------------
// hpre body: hpre tile = A @ B^T, n-split by half-head. (mb, h*2+ch) covers
// rows [mb*16,+16) x cols [h*128+ch*64,+64) (4 B-frags, 5 loads/kc).
// Epilogue: (a) half-B-frags of bf16(hpre) -> hbTf, (b) asrc/adst half-dots
// -> deterministic 2-way atomicAdd, (c) wave max -> atomicMax MhEncH.
// ---------------------------------------------------------------------------
template <int KC>
__device__ void hpre_body(const short* __restrict__ Af, const short* __restrict__ Bf,
                          const float* __restrict__ a_src, const float* __restrict__ a_dst,
                          short* __restrict__ hbTf, float* __restrict__ asrc,
                          float* __restrict__ adst, unsigned* __restrict__ MhEncH,
                          int mb, int hy)
{
    __shared__ __align__(16) short tileT[64][24];   // [localcol][localrow]
    const int lane = threadIdx.x;
    const int h    = hy >> 1;   // head
    const int ch   = hy & 1;    // col half
    const int i0   = mb * 16;

    f32x4 acc[4];
#pragma unroll
    for (int c = 0; c < 4; c++) acc[c] = (f32x4){0.f, 0.f, 0.f, 0.f};

    const short* ap = Af + (size_t)mb * KC * 512 + lane * 8;
    const short* bp = Bf + (size_t)(h * 8 + ch * 4) * KC * 512 + lane * 8;

#pragma unroll 2
    for (int kc = 0; kc < KC; kc++) {
        short8 a = *(const short8*)(ap + (size_t)kc * 512);
#pragma unroll
        for (int c = 0; c < 4; c++) {
            short8 bf = *(const short8*)(bp + ((size_t)c * KC + kc) * 512);
            acc[c] = __builtin_amdgcn_mfma_f32_16x16x32_bf16(a, bf, acc[c], 0, 0, 0);
        }
    }

    const int col = lane & 15, q4 = lane >> 4;

#pragma unroll
    for (int c = 0; c < 4; c++) {
        uint2 u;
        u.x = pk2(acc[c][0], acc[c][1]);
        u.y = pk2(acc[c][2], acc[c][3]);
        *(uint2*)&tileT[c * 16 + col][q4 * 4] = u;
    }
    __syncthreads();
    {
        const int jc = mb >> 1, khalf = mb & 1;
        const int nr = lane & 15, kq = lane >> 4;
        if ((kq >> 1) == khalf) {
#pragma unroll
            for (int cl = 0; cl < 4; cl++) {
                short8 v = *(const short8*)&tileT[cl * 16 + nr][(kq & 1) * 8];
                const int nbl = h * 8 + ch * 4 + cl;
                *(short8*)&hbTf[(((size_t)nbl * (CNODES / 32) + jc) * 64 + lane) * 8] = v;
            }
        }
    }

    float ssrc[4] = {}, sdst[4] = {};
#pragma unroll
    for (int c = 0; c < 4; c++) {
        const float vs = a_src[h * 128 + ch * 64 + c * 16 + col];
        const float vd = a_dst[h * 128 + ch * 64 + c * 16 + col];
#pragma unroll
        for (int r = 0; r < 4; r++) {
            ssrc[r] += acc[c][r] * vs;
            sdst[r] += acc[c][r] * vd;
        }
    }
#pragma unroll
    for (int mask = 1; mask <= 8; mask <<= 1)
#pragma unroll
        for (int r = 0; r < 4; r++) {
            ssrc[r] += __shfl_xor(ssrc[r], mask);
            sdst[r] += __shfl_xor(sdst[r], mask);
        }
    if (col == 0) {
#pragma unroll
        for (int r = 0; r < 4; r++) {
            const int row = i0 + q4 * 4 + r;
            atomicAdd(asrc + h * CNODES + row, ssrc[r]);   // exactly 2 contributors
            atomicAdd(adst + h * CNODES + row, sdst[r]);
        }
    }
    // wave max of half-dot -> one atomic per block
    float wmax = fmaxf(fmaxf(sdst[0], sdst[1]), fmaxf(sdst[2], sdst[3]));
    wmax = fmaxf(wmax, __shfl_xor(wmax, 16));
    wmax = fmaxf(wmax, __shfl_xor(wmax, 32));
    if (lane == 0) atomicMax(MhEncH + h * 2 + ch, encf(wmax));
}

// ---------------------------------------------------------------------------
// doc body: doc_h tile = relu(A @ B^T + bias) -> bf16 A-frags (dhf).
// ---------------------------------------------------------------------------
template <int KC>
__device__ void doc_body(const short* __restrict__ Af, const short* __restrict__ Bf,
                         const float* __restrict__ bias, short* __restrict__ dhf,
                         int mb, int ng)
{
    __shared__ __align__(16) short tile[16][32];
    const int lane = threadIdx.x;

    f32x4 acc[2];
#pragma unroll
    for (int c = 0; c < 2; c++) acc[c] = (f32x4){0.f, 0.f, 0.f, 0.f};

    const short* ap = Af + (size_t)mb * KC * 512 + lane * 8;
    const short* bp = Bf + (size_t)(ng * 2) * KC * 512 + lane * 8;

#pragma unroll 2
    for (int kc = 0; kc < KC; kc++) {
        short8 a = *(const short8*)(ap + (size_t)kc * 512);
#pragma unroll
        for (int c = 0; c < 2; c++) {
            short8 bf = *(const short8*)(bp + ((size_t)c * KC + kc) * 512);
            acc[c] = __builtin_amdgcn_mfma_f32_16x16x32_bf16(a, bf, acc[c], 0, 0, 0);
        }
    }

    const int col = lane & 15, q4 = lane >> 4;
#pragma unroll
    for (int c = 0; c < 2; c++)
#pragma unroll
        for (int r = 0; r < 4; r++) {
            float v = fmaxf(acc[c][r] + bias[ng * 32 + c * 16 + col], 0.f);
            tile[q4 * 4 + r][c * 16 + col] = f2bf(v);
        }
    __syncthreads();
    const int m = lane & 15, kq = lane >> 4;
    short8 v = *(const short8*)&tile[m][kq * 8];
    *(short8*)&dhf[(((size_t)mb * 16 + ng) * 64 + lane) * 8] = v;
}

// ---------------------------------------------------------------------------
// gemm_hd: fused hpre-L1 (2048 blocks) + doc (1024 blocks). The two are
// independent (both depend only on prep_all) -- fusing lets doc's blocks
// execute concurrently with hpre's instead of serializing on the stream.
// ---------------------------------------------------------------------------
template <int KC>
__global__ __launch_bounds__(64)
void gemm_hd(const short* __restrict__ Af, const short* __restrict__ Bf,
             const float* __restrict__ a_src, const float* __restrict__ a_dst,
             short* __restrict__ hbTf, float* __restrict__ asrc,
             float* __restrict__ adst, unsigned* __restrict__ MhEncH,
             const short* __restrict__ dAf, const short* __restrict__ dBf,
             const float* __restrict__ bias, short* __restrict__ dhf)
{
    const int b = blockIdx.x;
    if (b < 2048) {
        hpre_body<KC>(Af, Bf, a_src, a_dst, hbTf, asrc, adst, MhEncH, b >> 3, b & 7);
    } else {
        const int d = b - 2048;
        doc_body<KC>(dAf, dBf, bias, dhf, d >> 4, d & 15);
    }
}

// ---------------------------------------------------------------------------
// gemm_hpre: standalone (layer 2). grid (CNODES/16, 8).
// ---------------------------------------------------------------------------
template <int KC>
__global__ __launch_bounds__(64)
void gemm_hpre(const short* __restrict__ Af, const short* __restrict__ Bf,
               const float* __restrict__ a_src, const float* __restrict__ a_dst,
               short* __restrict__ hbTf, float* __restrict__ asrc, float* __restrict__ adst,
               unsigned* __restrict__ MhEncH)
{
    hpre_body<KC>(Af, Bf, a_src, a_dst, hbTf, asrc, adst, MhEncH,
                  blockIdx.x, blockIdx.y);
}

// ---------------------------------------------------------------------------
// gemm_frag: C[M][N] fp32 = A @ B^T from bf16 fragments (logits).
// m-tile 64, n-tile 64: per k-step 8 loads : 16 MFMA.
// grid (BDOCS/64, CNODES/64) = (16, 64) = 1024 one-wave blocks.
// ---------------------------------------------------------------------------
template <int KC>
__global__ __launch_bounds__(64)
void gemm_frag(const short* __restrict__ Af, const short* __restrict__ Bf,
               float* __restrict__ Cmat, int N)
{
    const int lane = threadIdx.x;
    const int mb0  = blockIdx.x * 4;
    const int ng   = blockIdx.y;    // 64-col group

    f32x4 acc[4][4];
#pragma unroll
    for (int f = 0; f < 4; f++)
#pragma unroll
        for (int c = 0; c < 4; c++) acc[f][c] = (f32x4){0.f, 0.f, 0.f, 0.f};

    const short* ap = Af + (size_t)mb0 * KC * 512 + lane * 8;
    const short* bp = Bf + (size_t)(ng * 4) * KC * 512 + lane * 8;

#pragma unroll 2
    for (int kc = 0; kc < KC; kc++) {
        short8 a0 = *(const short8*)(ap + ((size_t)0 * KC + kc) * 512);
        short8 a1 = *(const short8*)(ap + ((size_t)1 * KC + kc) * 512);
        short8 a2 = *(const short8*)(ap + ((size_t)2 * KC + kc) * 512);
        short8 a3 = *(const short8*)(ap + ((size_t)3 * KC + kc) * 512);
#pragma unroll
        for (int c = 0; c < 4; c++) {
            short8 bf = *(const short8*)(bp + ((size_t)c * KC + kc) * 512);
            acc[0][c] = __builtin_amdgcn_mfma_f32_16x16x32_bf16(a0, bf, acc[0][c], 0, 0, 0);
            acc[1][c] = __builtin_amdgcn_mfma_f32_16x16x32_bf16(a1, bf, acc[1][c], 0, 0, 0);
            acc[2][c] = __builtin_amdgcn_mfma_f32_16x16x32_bf16(a2, bf, acc[2][c], 0, 0, 0);
            acc[3][c] = __builtin_amdgcn_mfma_f32_16x16x32_bf16(a3, bf, acc[3][c], 0, 0, 0);
        }
    }

    const int col = lane & 15, q4 = lane >> 4;
#pragma unroll
    for (int f = 0; f < 4; f++)
#pragma unroll
        for (int c = 0; c < 4; c++)
#pragma unroll
            for (int r = 0; r < 4; r++) {
                const int row = (mb0 + f) * 16 + q4 * 4 + r;
                Cmat[(size_t)row * N + ng * 64 + c * 16 + col] = acc[f][c][r];
            }
}

// ---------------------------------------------------------------------------
// attn_pv: partial[ks][i][n] (bf16) = sum_{j in slice} w_ij * V[j][n].
// 512-thread blocks = 8 waves (wave = (i-half, head)), E1/E2 in LDS preamble,
// Mh = sum of half maxima (upper bound; weights exact). grid (64, 8).
// BYTE-IDENTICAL to the 57.9us round-1 version: the 88-VGPR deep-prefetch
// schedule is fragile -- max-form weights, union packs, and s_setprio all
// collapsed it to a 76-VGPR shallow schedule (80-95us). DO NOT TOUCH.
// ---------------------------------------------------------------------------
__global__ __launch_bounds__(512, 2)
void attn_pv(const short* __restrict__ hbTf,
             const unsigned int* __restrict__ adjb,
             const float* __restrict__ asrc, const float* __restrict__ adst,
             const unsigned* __restrict__ MhEncH,
             short* __restrict__ part, float* __restrict__ lpart)
{
    __shared__ __align__(16) float E1s[NHEAD][512];    // 8 KB
    __shared__ __align__(16) float E2s[NHEAD][512];    // 8 KB
    __shared__ __align__(16) short tileO[32][520];     // 33.3 KB

    const int t    = threadIdx.x;
    const int ww   = t >> 6;
    const int w    = ww & 3;        // head
    const int f2   = ww >> 2;       // i-half (0/1)
    const int lane = t & 63;
    const int m    = lane & 15;
    const int kq   = lane >> 4;
    const int i0   = blockIdx.x * 64;
    const int iw   = i0 + f2 * 32;
    const int ks   = blockIdx.y;
    const int js   = ks * JPER;

    // ---- preamble: E1/E2 for this slice into LDS (t indexes j) ----
    {
        const int j = js + t;
#pragma unroll
        for (int h = 0; h < NHEAD; h++) {
            const float mhh = decf(MhEncH[h * 2]) + decf(MhEncH[h * 2 + 1]);
            const float d = adst[h * CNODES + j] - mhh;
            E1s[h][t] = __expf(d);
            E2s[h][t] = __expf(0.2f * d);
        }
    }

    const float mh  = decf(MhEncH[w * 2]) + decf(MhEncH[w * 2 + 1]);
    const float as0 = asrc[w * CNODES + iw + m];
    const float as1 = asrc[w * CNODES + iw + 16 + m];
    const float mr0 = lrelu(as0 + mh), mr1 = lrelu(as1 + mh);
    const float A10 = __expf(as0 + mh - mr0),          A11 = __expf(as1 + mh - mr1);
    const float A20 = __expf(0.2f * (as0 + mh) - mr0), A21 = __expf(0.2f * (as1 + mh) - mr1);
    const float T00 = __expf(-as0 - mh),               T01 = __expf(-as1 - mh);

    f32x4 acc[2][8], accO[2];
#pragma unroll
    for (int f = 0; f < 2; f++) {
        accO[f] = (f32x4){0.f, 0.f, 0.f, 0.f};
#pragma unroll
        for (int c = 0; c < 8; c++) acc[f][c] = (f32x4){0.f, 0.f, 0.f, 0.f};
    }
    short8 ones;
#pragma unroll
    for (int q = 0; q < 8; q++) ones[q] = (short)0x3F80;   // bf16 1.0

    const unsigned int* ar0 = adjb + (size_t)(iw + m) * 128 + ks * NCH;
    const unsigned int* ar1 = adjb + (size_t)(iw + 16 + m) * 128 + ks * NCH;

    __syncthreads();   // E LDS ready

#pragma unroll 2
    for (int ch = 0; ch < NCH; ch++) {
        const int jl = ch * 32;
        const unsigned int aw0 = ar0[ch] >> (kq * 8);
        const unsigned int aw1 = ar1[ch] >> (kq * 8);
        const float4 x0 = *(const float4*)&E1s[w][jl + kq * 8];
        const float4 x1 = *(const float4*)&E1s[w][jl + kq * 8 + 4];
        const float4 y0 = *(const float4*)&E2s[w][jl + kq * 8];
        const float4 y1 = *(const float4*)&E2s[w][jl + kq * 8 + 4];
        const float e1v[8] = {x0.x, x0.y, x0.z, x0.w, x1.x, x1.y, x1.z, x1.w};
        const float e2v[8] = {y0.x, y0.y, y0.z, y0.w, y1.x, y1.y, y1.z, y1.w};

        short8 a0, a1;
#pragma unroll
        for (int q = 0; q < 8; q++) {
            const float e1 = e1v[q], e2 = e2v[q];
            const bool c0 = e1 > T00, c1 = e1 > T01;
            float w0 = (c0 ? A10 : A20) * (c0 ? e1 : e2);
            float w1 = (c1 ? A11 : A21) * (c1 ? e1 : e2);
            w0 = ((aw0 >> q) & 1u) ? w0 : 0.f;
            w1 = ((aw1 >> q) & 1u) ? w1 : 0.f;
            a0[q] = hup(w0);
            a1[q] = hup(w1);
        }

        const short* bbase = hbTf + (((size_t)(w * 8) * 128 + ((js + jl) >> 5)) * 64 + lane) * 8;
#pragma unroll
        for (int c = 0; c < 8; c++) {
            short8 bf = *(const short8*)(bbase + (size_t)c * 128 * 64 * 8);
            acc[0][c] = __builtin_amdgcn_mfma_f32_16x16x32_bf16(a0, bf, acc[0][c], 0, 0, 0);
            acc[1][c] = __builtin_amdgcn_mfma_f32_16x16x32_bf16(a1, bf, acc[1][c], 0, 0, 0);
        }
        accO[0] = __builtin_amdgcn_mfma_f32_16x16x32_bf16(a0, ones, accO[0], 0, 0, 0);
        accO[1] = __builtin_amdgcn_mfma_f32_16x16x32_bf16(a1, ones, accO[1], 0, 0, 0);
    }

    if (m == 0) {
#pragma unroll
        for (int f = 0; f < 2; f++)
#pragma unroll
            for (int r = 0; r < 4; r++)
                lpart[((size_t)ks * NHEAD + w) * CNODES + iw + f * 16 + kq * 4 + r] = accO[f][r];
    }

    // bf16 partials via 32-row LDS tile, one round per i-half
    short* pS = part + (size_t)ks * CNODES * HID;
    for (int half = 0; half < 2; half++) {
        __syncthreads();
        if (f2 == half) {
#pragma unroll
            for (int f = 0; f < 2; f++)
#pragma unroll
                for (int c = 0; c < 8; c++)
#pragma unroll
                    for (int r = 0; r < 4; r++)
                        tileO[f * 16 + kq * 4 + r][w * 128 + c * 16 + m] = f2bf(acc[f][c][r]);
        }
        __syncthreads();
#pragma unroll
        for (int it = 0; it < 4; it++) {
            const int u   = it * 512 + t;
            const int row = u >> 6, un = u & 63;
            uint4 v = *(const uint4*)&tileO[row][un * 8];
            *(uint4*)&pS[(size_t)(i0 + half * 32 + row) * HID + un * 8] = v;
        }
    }
}

// ---------------------------------------------------------------------------
// reduce_norm_frag: out = (sum_s part)/(sum_s lpart), optional ELU, written
// as bf16 fragments. Coalesced: one wave reads one (s,i) row contiguously
// (64 lanes x 16B = 1KB); accumulate in registers, normalize, stage 16-row
// tile in LDS, emit fragments. Grid: CNODES/16 = 256 blocks x 256 threads.
// When ZERO (layer-1 pass), the first 32 blocks also zero asrc/adst for L2.
// ---------------------------------------------------------------------------
template <bool ELU, bool ZERO>
__global__ __launch_bounds__(256)
void reduce_norm_frag(const short* __restrict__ part, const float* __restrict__ lpart,
                      short* __restrict__ dst, float4* __restrict__ accZero)
{
    __shared__ __align__(16) short rowbuf[16][520];   // 16.6 KB, stride 1040B (2-way max)

    const int t    = threadIdx.x;
    const int wv   = t >> 6;        // wave 0..3
    const int lane = t & 63;
    const int rb   = blockIdx.x;    // 16-row block

    if (ZERO && blockIdx.x < 32)
        accZero[blockIdx.x * 256 + t] = (float4){0.f, 0.f, 0.f, 0.f};

    const int h = lane >> 4;        // head for this lane's column range (n0 = lane*8)

#pragma unroll
    for (int r = 0; r < 4; r++) {
        const int i = rb * 16 + wv * 4 + r;
        float v[8] = {};
        float l = 0.f;
#pragma unroll
        for (int s = 0; s < KSPLIT; s++) {
            const uint4 raw = *(const uint4*)&part[(size_t)s * CNODES * HID
                                                   + (size_t)i * HID + lane * 8];
            const unsigned rr[4] = {raw.x, raw.y, raw.z, raw.w};
#pragma unroll
            for (int q = 0; q < 4; q++) {
                v[q * 2]     += bf2f((short)(rr[q] & 0xffff));
                v[q * 2 + 1] += bf2f((short)(rr[q] >> 16));
            }
            l += lpart[((size_t)s * NHEAD + h) * CNODES + i];
        }
        const float inv = 1.0f / l;
        short8 o;
#pragma unroll
        for (int q = 0; q < 8; q++) {
            float x = v[q] * inv;
            if (ELU) x = x > 0.f ? x : (__expf(x) - 1.f);
            o[q] = f2bf(x);
        }
        *(short8*)&rowbuf[wv * 4 + r][lane * 8] = o;
    }
    __syncthreads();

    const int m  = lane & 15;
    const int kq = lane >> 4;
#pragma unroll
    for (int j = 0; j < 4; j++) {
        const int kc = wv + j * 4;
        short8 v = *(const short8*)&rowbuf[m][kc * 32 + kq * 8];
        *(short8*)&dst[(((size_t)rb * 16 + kc) * 64 + lane) * 8] = v;
    }
}

// ---------------------------------------------------------------------------
extern "C" void kernel_launch(void* const* d_in, const int* in_sizes, int n_in,
                              void* d_out, int out_size, void* d_ws, size_t ws_size,
                              hipStream_t stream)
{
    const float* doc_x      = (const float*)d_in[0];
    const float* label_init = (const float*)d_in[1];
    const int*   adj        = (const int*)d_in[2];
    const float* W1         = (const float*)d_in[3];
    const float* a_src1     = (const float*)d_in[4];
    const float* a_dst1     = (const float*)d_in[5];
    const float* W2         = (const float*)d_in[6];
    const float* a_src2     = (const float*)d_in[7];
    const float* a_dst2     = (const float*)d_in[8];
    const float* Wd         = (const float*)d_in[9];
    const float* bd         = (const float*)d_in[10];
    float*       out        = (float*)d_out;

    char* wsb = (char*)d_ws;
    size_t off = 0;
    auto alloc = [&](size_t bytes) -> char* {
        char* p = wsb + off;
        off = (off + bytes + 255) & ~(size_t)255;
        return p;
    };

    float* asrc  = (float*)alloc(NHEAD * CNODES * 4);   // zeroed in-kernel
    float* adst  = (float*)alloc(NHEAD * CNODES * 4);   // contiguous after asrc
    unsigned* MhEncH = (unsigned*)alloc(256);           // 0..7 L1 halves, 8..15 L2
    float* lpart = (float*)alloc((size_t)KSPLIT * NHEAD * CNODES * 4);
    unsigned int* adjb = (unsigned int*)alloc((size_t)CNODES * 128 * 4);   // 2 MB
    short* hbTf  = (short*)alloc((size_t)CNODES * HID * 2);                // 4 MB
    short* Wdf   = (short*)alloc((size_t)INDIM * HID * 2);
    short* W1f   = (short*)alloc((size_t)INDIM * HID * 2);
    short* W2f   = (short*)alloc((size_t)HID * HID * 2);
    short* dxf   = (short*)alloc((size_t)BDOCS * INDIM * 2);
    short* Af_li = (short*)alloc((size_t)CNODES * INDIM * 2);              // 6 MB
    short* Af2   = (short*)alloc((size_t)CNODES * HID * 2);                // 4 MB
    short* lhf   = (short*)alloc((size_t)CNODES * HID * 2);                // 4 MB
    short* dhf   = (short*)alloc((size_t)BDOCS * HID * 2);                 // 1 MB
    short* part  = (short*)alloc((size_t)KSPLIT * CNODES * HID * 2);       // 32 MB
    (void)ws_size;

    const dim3 blk(256);

    // all one-time transforms + asrc/adst zeroing in a single dispatch
    prep_all<<<PREP_BLOCKS, blk, 0, stream>>>(adj, (unsigned long long*)adjb,
                                              Wd, Wdf, W1, W1f, W2, W2f,
                                              doc_x, dxf, label_init, Af_li, MhEncH,
                                              (float4*)asrc);

    // fused: hpre1 (label_init @ W1 -> hbTf/asrc/adst/Mh) + doc_h (relu gemm)
    gemm_hd<INDIM / 32><<<2048 + 1024, 64, 0, stream>>>(
        Af_li, W1f, a_src1, a_dst1, hbTf, asrc, adst, MhEncH,
        dxf, Wdf, bd, dhf);

    // GAT layer 1
    attn_pv<<<dim3(CNODES / 64, KSPLIT), 512, 0, stream>>>(
        hbTf, adjb, asrc, adst, MhEncH, part, lpart);
    reduce_norm_frag<true, true><<<CNODES / 16, blk, 0, stream>>>(
        part, lpart, Af2, (float4*)asrc);   // also zeroes asrc/adst for L2

    // hpre2 = elu(gat1) @ W2 -> hbTf B-frags + asrc/adst + Mh halves (fused)
    gemm_hpre<HID / 32><<<dim3(CNODES / 16, 2 * NHEAD), 64, 0, stream>>>(
        Af2, W2f, a_src2, a_dst2, hbTf, asrc, adst, MhEncH + 8);

    // GAT layer 2
    attn_pv<<<dim3(CNODES / 64, KSPLIT), 512, 0, stream>>>(
        hbTf, adjb, asrc, adst, MhEncH + 8, part, lpart);
    reduce_norm_frag<false, false><<<CNODES / 16, blk, 0, stream>>>(
        part, lpart, lhf, nullptr);

    // logits = doc_h @ label_h^T -> out (64x64 tiles, 1024 blocks)
    gemm_frag<HID / 32><<<dim3(BDOCS / 64, CNODES / 64), 64, 0, stream>>>(dhf, lhf, out, CNODES);
}